// Round 1
// baseline (388.476 us; speedup 1.0000x reference)
//
#include <hip/hip_runtime.h>
#include <hip/hip_bf16.h>
#include <stdint.h>

#define HW 16384

typedef __bf16 bf16_t;
typedef bf16_t bf16x8 __attribute__((ext_vector_type(8)));
typedef float f32x4 __attribute__((ext_vector_type(4)));

// tanh-form GELU via hw exp2 + hw rcp:
// gelu(x) = x * sigmoid(1.5957691*(x + 0.044715 x^3)); 1.5957691*log2(e)=2.3022083
__device__ __forceinline__ float gelu_f(float x) {
    float t = x * fmaf(x * x, 0.044715f, 1.0f);
    float e = __builtin_amdgcn_exp2f(-2.3022083f * t);
    return x * __builtin_amdgcn_rcpf(1.0f + e);
}

__device__ __forceinline__ uint32_t pk2(float a, float b) {
    union { bf16_t h[2]; uint32_t u; } z;
    z.h[0] = (bf16_t)a; z.h[1] = (bf16_t)b;
    return z.u;
}

// async global->LDS, 16B per lane; LDS dest = uniform base + lane*16
__device__ __forceinline__ void load16_to_lds(const float* g, float* lds) {
    __builtin_amdgcn_global_load_lds(
        (const __attribute__((address_space(1))) uint32_t*)g,
        (__attribute__((address_space(3))) uint32_t*)lds, 16, 0, 0);
}

// load 8 consecutive fp32 -> bf16x8 fragment (32B aligned source)
__device__ __forceinline__ bf16x8 frag8(const float* src) {
    float4 lo = ((const float4*)src)[0];
    float4 hi = ((const float4*)src)[1];
    bf16x8 r;
    r[0] = (bf16_t)lo.x; r[1] = (bf16_t)lo.y; r[2] = (bf16_t)lo.z; r[3] = (bf16_t)lo.w;
    r[4] = (bf16_t)hi.x; r[5] = (bf16_t)hi.y; r[6] = (bf16_t)hi.z; r[7] = (bf16_t)hi.w;
    return r;
}

// ---------------------------------------------------------------------------
// Kernel 1: features = gelu(fe_w @ x + fe_b) -> bf16 pixel-major, + gf partial.
// Depth-2 DMA pipeline over 64-px tiles:
//   LDS xs[2][64 rows][64 px] (2 x 16 KB), raw s_barrier + counted vmcnt.
// Chunk XOR swizzle (global-side pre-swizzle): LDS row c, 16B-chunk m holds
// global chunk m ^ (((c>>3)&3)<<2); reader dword = c*64 + 16*(wid^g) + r16
// -> 2-way bank aliasing only (free).
// Grid: 32 samples * 32 superstripes; block = 4 waves; 8 tiles per block.
// vmcnt discipline (per-wave, in-order retirement):
//   steady state at wait: [S_{i+1} 4L][V_i 4 stores][S_{i+2} 4L] -> vmcnt(8).
// ---------------------------------------------------------------------------
__global__ __launch_bounds__(256, 4)
void k1_feat(const float* __restrict__ x, const float* __restrict__ fe_w,
             const float* __restrict__ fe_b, bf16_t* __restrict__ feat,
             float* __restrict__ gf_part) {
    __shared__ float xs[2][64 * 64];   // 2 x 16 KB
    __shared__ float gf4[4][64];

    int tid = threadIdx.x;
    int lane = tid & 63;
    int wid = tid >> 6;
    int r16 = lane & 15;
    int g = lane >> 4;
    int b = blockIdx.x >> 5;
    int ss = blockIdx.x & 31;
    int p0 = ss * 512;

    // A fragments (fe_w as MFMA A: row = out-ch = r16, k = kh*32 + g*8 + j)
    // issued FIRST so their auto-waitcnt never drains the staging queue.
    bf16x8 A[4][2];
    f32x4 bias[4];
#pragma unroll
    for (int ot = 0; ot < 4; ++ot) {
#pragma unroll
        for (int kh = 0; kh < 2; ++kh)
            A[ot][kh] = frag8(fe_w + (ot * 16 + r16) * 64 + kh * 32 + g * 8);
#pragma unroll
        for (int r = 0; r < 4; ++r) bias[ot][r] = fe_b[ot * 16 + g * 4 + r];
    }

    int j16 = lane & 15;   // 16B chunk within row
    int rsub = lane >> 4;  // row within 4-row group

    auto STAGE = [&](int buf, int i) {
#pragma unroll
        for (int s = 0; s < 4; ++s) {
            int c0 = wid * 16 + s * 4;             // first row of this instr
            int c = c0 + rsub;                     // this lane's row
            int gch = j16 ^ (((c >> 3) & 3) << 2); // pre-swizzled global chunk
            const float* gsrc = x + (size_t)(b * 64 + c) * HW + p0 + i * 64 + gch * 4;
            load16_to_lds(gsrc, &xs[buf][c0 * 64]);  // uniform base per instr
        }
    };

    float gfp[4][4] = {};
    bf16_t* featb = feat + (size_t)b * HW * 64;
    int wb = 16 * (wid ^ g) + r16;                 // swizzled read dword in row

    auto COMPUTE = [&](int buf, int i) {
        bf16x8 B0, B1;
#pragma unroll
        for (int j = 0; j < 8; ++j) {
            B0[j] = (bf16_t)xs[buf][(g * 8 + j) * 64 + wb];
            B1[j] = (bf16_t)xs[buf][(32 + g * 8 + j) * 64 + wb];
        }
        int pg = p0 + i * 64 + wid * 16 + r16;
#pragma unroll
        for (int ot = 0; ot < 4; ++ot) {
            f32x4 y = {0.f, 0.f, 0.f, 0.f};
            y = __builtin_amdgcn_mfma_f32_16x16x32_bf16(A[ot][0], B0, y, 0, 0, 0);
            y = __builtin_amdgcn_mfma_f32_16x16x32_bf16(A[ot][1], B1, y, 0, 0, 0);
            float vr[4];
#pragma unroll
            for (int r = 0; r < 4; ++r) {
                float v = gelu_f(y[r] + bias[ot][r]);
                gfp[ot][r] += v;
                vr[r] = v;
            }
            uint2 st;
            st.x = pk2(vr[0], vr[1]);
            st.y = pk2(vr[2], vr[3]);
            *(uint2*)(featb + (size_t)pg * 64 + ot * 16 + g * 4) = st;
        }
    };

    // prologue: fill both buffers; wait own S0 (A-loads 16L + S0 4L + S1 4L
    // in flight -> vmcnt(4) guarantees A and S0 retired, most of S1 too).
    STAGE(0, 0);
    STAGE(1, 1);
    asm volatile("s_waitcnt vmcnt(4)" ::: "memory");
    __builtin_amdgcn_s_barrier();

#pragma unroll
    for (int i = 0; i < 8; ++i) {
        COMPUTE(i & 1, i);                          // 4 feat stores issued
        asm volatile("s_waitcnt lgkmcnt(0)" ::: "memory");
        __builtin_amdgcn_s_barrier();               // all waves done reading buf
        if (i < 6) {
            STAGE(i & 1, i + 2);                    // overwrite just-read buf
            // outstanding: [S_{i+1} 4L][V_i 4S][S_{i+2} 4L] -> keep 8 newest
            asm volatile("s_waitcnt vmcnt(8)" ::: "memory");
            __builtin_amdgcn_s_barrier();
        } else if (i == 6) {
            // outstanding: [V5 4S][S7 4L][V6 4S] -> keep 4 newest
            asm volatile("s_waitcnt vmcnt(4)" ::: "memory");
            __builtin_amdgcn_s_barrier();
        }
    }

    // cross-wave gf reduction -> per-block partial (no atomics)
#pragma unroll
    for (int ot = 0; ot < 4; ++ot)
#pragma unroll
        for (int r = 0; r < 4; ++r) {
            float v = gfp[ot][r];
            v += __shfl_xor(v, 1);
            v += __shfl_xor(v, 2);
            v += __shfl_xor(v, 4);
            v += __shfl_xor(v, 8);
            if (r16 == 0) gf4[wid][ot * 16 + g * 4 + r] = v;
        }
    __syncthreads();
    if (tid < 64)
        gf_part[(size_t)blockIdx.x * 64 + tid] =
            gf4[0][tid] + gf4[1][tid] + gf4[2][tid] + gf4[3][tid];
}

// ---------------------------------------------------------------------------
// Kernel 2: gating MLP. One block per sample (grid=32). Reduces k1's 32
// per-superstripe partials, then LDS-staged matvec chain (2-way split chains).
// ---------------------------------------------------------------------------
__global__ __launch_bounds__(256)
void k2_gate(const float* __restrict__ gf_part,
             const float* __restrict__ g1_w, const float* __restrict__ g1_b,
             const float* __restrict__ bn1_g, const float* __restrict__ bn1_b,
             const float* __restrict__ ca1_w, const float* __restrict__ ca1_b,
             const float* __restrict__ ca2_w, const float* __restrict__ ca2_b,
             const float* __restrict__ g2_w, const float* __restrict__ g2_b,
             const float* __restrict__ bn2_g, const float* __restrict__ bn2_b,
             const float* __restrict__ g3_w, const float* __restrict__ g3_b,
             int* __restrict__ gidx, float* __restrict__ gw) {
    __shared__ float w1t[128 * 65];    // g1_w padded
    __shared__ float wc1[8 * 129];     // ca1_w padded
    __shared__ float wc2[128 * 9];     // ca2_w padded
    __shared__ float w2t[64 * 129];    // g2_w padded
    __shared__ float w3[8 * 65];       // g3_w padded
    __shared__ float gf[64], h1[128], a1[8], hh[64], sc[8];
    const float R1 = 0.99999500003749969f;   // 1/sqrt(1+1e-5)
    int tid = threadIdx.x;
    int b = blockIdx.x;

    // stage weights: coalesced float4 global loads -> padded LDS rows
    for (int i = tid; i < 2048; i += 256) {        // g1_w [128][64]
        float4 v = ((const float4*)g1_w)[i];
        float* d = w1t + (i >> 4) * 65 + (i & 15) * 4;
        d[0] = v.x; d[1] = v.y; d[2] = v.z; d[3] = v.w;
    }
    for (int i = tid; i < 2048; i += 256) {        // g2_w [64][128]
        float4 v = ((const float4*)g2_w)[i];
        float* d = w2t + (i >> 5) * 129 + (i & 31) * 4;
        d[0] = v.x; d[1] = v.y; d[2] = v.z; d[3] = v.w;
    }
    if (tid < 256) {                               // ca1_w [8][128]
        int i = tid;
        float4 v = ((const float4*)ca1_w)[i];
        float* d = wc1 + (i >> 5) * 129 + (i & 31) * 4;
        d[0] = v.x; d[1] = v.y; d[2] = v.z; d[3] = v.w;
    }
    if (tid < 256) {                               // ca2_w [128][8]
        int i = tid;
        float4 v = ((const float4*)ca2_w)[i];
        float* d = wc2 + (i >> 1) * 9 + (i & 1) * 4;
        d[0] = v.x; d[1] = v.y; d[2] = v.z; d[3] = v.w;
    }
    if (tid < 128) {                               // g3_w [8][64]
        int i = tid;
        float4 v = ((const float4*)g3_w)[i];
        float* d = w3 + (i >> 4) * 65 + (i & 15) * 4;
        d[0] = v.x; d[1] = v.y; d[2] = v.z; d[3] = v.w;
    }
    if (tid < 64) {                                // reduce k1 partials
        float s0 = 0.f, s1 = 0.f;
#pragma unroll
        for (int ssi = 0; ssi < 32; ssi += 2) {
            s0 += gf_part[(size_t)(b * 32 + ssi) * 64 + tid];
            s1 += gf_part[(size_t)(b * 32 + ssi + 1) * 64 + tid];
        }
        gf[tid] = (s0 + s1) * (1.0f / 16384.0f);
    }
    __syncthreads();

    if (tid < 128) {                 // h1 = gelu(bn(g1))
        int j = tid;
        float s0 = 0.f, s1 = 0.f;
#pragma unroll 8
        for (int c = 0; c < 64; c += 2) {
            s0 += gf[c] * w1t[j * 65 + c];
            s1 += gf[c + 1] * w1t[j * 65 + c + 1];
        }
        float s = g1_b[j] + s0 + s1;
        s = s * (bn1_g[j] * R1) + bn1_b[j];
        h1[j] = gelu_f(s);
    }
    __syncthreads();
    if (tid < 8) {                   // a1 = gelu(ca1)
        int j = tid;
        float s0 = 0.f, s1 = 0.f;
#pragma unroll 8
        for (int c = 0; c < 128; c += 2) {
            s0 += h1[c] * wc1[j * 129 + c];
            s1 += h1[c + 1] * wc1[j * 129 + c + 1];
        }
        a1[j] = gelu_f(ca1_b[j] + s0 + s1);
    }
    __syncthreads();
    if (tid < 128) {                 // h1 *= sigmoid(2*att)
        int j = tid;
        float s = ca2_b[j];
#pragma unroll
        for (int r = 0; r < 8; ++r) s += a1[r] * wc2[j * 9 + r];
        float e2 = __builtin_amdgcn_exp2f(-2.8853901f * s);  // 2*log2(e)
        h1[j] = h1[j] * __builtin_amdgcn_rcpf(1.0f + e2);
    }
    __syncthreads();
    if (tid < 64) {                  // hh = gelu(bn(g2))
        int j = tid;
        float s0 = 0.f, s1 = 0.f;
#pragma unroll 8
        for (int c = 0; c < 128; c += 2) {
            s0 += h1[c] * w2t[j * 129 + c];
            s1 += h1[c + 1] * w2t[j * 129 + c + 1];
        }
        float s = g2_b[j] + s0 + s1;
        s = s * (bn2_g[j] * R1) + bn2_b[j];
        hh[j] = gelu_f(s);
    }
    __syncthreads();
    if (tid < 8) {                   // scores
        int j = tid;
        float s0 = 0.f, s1 = 0.f;
#pragma unroll 8
        for (int c = 0; c < 64; c += 2) {
            s0 += hh[c] * w3[j * 65 + c];
            s1 += hh[c + 1] * w3[j * 65 + c + 1];
        }
        sc[j] = g3_b[j] + s0 + s1;
    }
    __syncthreads();
    if (tid == 0) {
        float v0 = -1e30f, v1 = -1e30f;
        int i0 = 0, i1 = 0;
#pragma unroll
        for (int e = 0; e < 8; ++e) {
            float s = sc[e];
            if (s > v0) { v1 = v0; i1 = i0; v0 = s; i0 = e; }
            else if (s > v1) { v1 = s; i1 = e; }
        }
        float t = __builtin_amdgcn_exp2f(0.7213475f * (v1 - v0));  // 0.5*log2(e)
        float den = __builtin_amdgcn_rcpf(1.0f + t);
        gidx[b * 2] = i0; gidx[b * 2 + 1] = i1;
        gw[b * 2] = den; gw[b * 2 + 1] = t * den;
    }
}

// ---------------------------------------------------------------------------
// Kernel 3: out = 0.5*(gelu(s0)+gelu(s1)) + w0*gelu(e[i0]) + w1*gelu(e[i1]).
// Operand-swapped MFMA: A = feat pixels (row=px=r16, k=channel), B = weight
// fragment (col=out-ch=r16, k=in-ch) -> D row = px = g*4+r, col = out-ch.
// Each lane owns 4 CONSECUTIVE pixels of one channel -> float4 stores.
// Weight frags converted inline from fp32 (k0 eliminated). Next-tile feat
// loads prefetched into registers.
// ---------------------------------------------------------------------------
__global__ __launch_bounds__(256, 4)
void k3_out(const bf16_t* __restrict__ feat, const float* __restrict__ s_w,
            const float* __restrict__ s_b, const float* __restrict__ e_w,
            const float* __restrict__ e_b, const int* __restrict__ gidx,
            const float* __restrict__ gw, float* __restrict__ out) {
    int tid = threadIdx.x;
    int lane = tid & 63, wid = tid >> 6;
    int r16 = lane & 15, g = lane >> 4;
    int b = blockIdx.x >> 5;
    int stripe = blockIdx.x & 31;

    int i0 = gidx[2 * b], i1 = gidx[2 * b + 1];
    float coef[4] = {0.5f, 0.5f, gw[2 * b], gw[2 * b + 1]};
    const float* Wm[4] = {s_w, s_w + 4096,
                          e_w + (size_t)i0 * 4096, e_w + (size_t)i1 * 4096};
    const float* Bv[4] = {s_b, s_b + 64, e_b + i0 * 64, e_b + i1 * 64};

    bf16x8 Wf[4][2];
    float bias[4];
    int row = wid * 16 + r16;                      // this lane's out-channel
#pragma unroll
    for (int m = 0; m < 4; ++m) {
#pragma unroll
        for (int kh = 0; kh < 2; ++kh)
            Wf[m][kh] = frag8(Wm[m] + row * 64 + kh * 32 + g * 8);
        bias[m] = Bv[m][row];
    }

    const uint4* fb = (const uint4*)(feat + (size_t)b * HW * 64);
    float* outb = out + ((size_t)b * 64 + row) * HW + stripe * 512;
    int pbase = stripe * 512 + r16;

    auto BODY = [&](int t, uint4 u0, uint4 u1) {
        bf16x8 F0 = __builtin_bit_cast(bf16x8, u0);
        bf16x8 F1 = __builtin_bit_cast(bf16x8, u1);
        f32x4 acc = {0.f, 0.f, 0.f, 0.f};
#pragma unroll
        for (int m = 0; m < 4; ++m) {
            f32x4 y = {0.f, 0.f, 0.f, 0.f};
            y = __builtin_amdgcn_mfma_f32_16x16x32_bf16(F0, Wf[m][0], y, 0, 0, 0);
            y = __builtin_amdgcn_mfma_f32_16x16x32_bf16(F1, Wf[m][1], y, 0, 0, 0);
#pragma unroll
            for (int r = 0; r < 4; ++r)
                acc[r] += coef[m] * gelu_f(y[r] + bias[m]);
        }
        float4 st = {acc[0], acc[1], acc[2], acc[3]};
        *(float4*)(outb + t * 16 + g * 4) = st;     // 4 consecutive pixels
    };

    uint4 u0 = fb[(size_t)pbase * 8 + g];
    uint4 u1 = fb[(size_t)pbase * 8 + 4 + g];
#pragma unroll 4
    for (int t = 0; t < 31; ++t) {
        uint4 n0 = fb[(size_t)(pbase + (t + 1) * 16) * 8 + g];
        uint4 n1 = fb[(size_t)(pbase + (t + 1) * 16) * 8 + 4 + g];
        BODY(t, u0, u1);
        u0 = n0; u1 = n1;
    }
    BODY(31, u0, u1);
}

extern "C" void kernel_launch(void* const* d_in, const int* in_sizes, int n_in,
                              void* d_out, int out_size, void* d_ws, size_t ws_size,
                              hipStream_t stream) {
    (void)in_sizes; (void)n_in; (void)out_size; (void)ws_size;
    const float* x     = (const float*)d_in[0];
    const float* fe_w  = (const float*)d_in[1];
    const float* fe_b  = (const float*)d_in[2];
    const float* s_w   = (const float*)d_in[3];
    const float* s_b   = (const float*)d_in[4];
    const float* e_w   = (const float*)d_in[5];
    const float* e_b   = (const float*)d_in[6];
    const float* g1_w  = (const float*)d_in[7];
    const float* g1_b  = (const float*)d_in[8];
    const float* bn1_g = (const float*)d_in[9];
    const float* bn1_b = (const float*)d_in[10];
    const float* ca1_w = (const float*)d_in[11];
    const float* ca1_b = (const float*)d_in[12];
    const float* ca2_w = (const float*)d_in[13];
    const float* ca2_b = (const float*)d_in[14];
    const float* g2_w  = (const float*)d_in[15];
    const float* g2_b  = (const float*)d_in[16];
    const float* bn2_g = (const float*)d_in[17];
    const float* bn2_b = (const float*)d_in[18];
    const float* g3_w  = (const float*)d_in[19];
    const float* g3_b  = (const float*)d_in[20];
    float* out = (float*)d_out;

    char* wsb = (char*)d_ws;
    bf16_t* feat   = (bf16_t*)wsb;                           // 64 MiB bf16 features
    float* gf_part = (float*)(wsb + 67108864);               // 256 KiB partials
    int* gidx      = (int*)(wsb + 67108864 + 262144);        // 256 B
    float* gwts    = (float*)(wsb + 67108864 + 262144 + 256);// 256 B

    k1_feat<<<1024, 256, 0, stream>>>(x, fe_w, fe_b, feat, gf_part);
    k2_gate<<<32, 256, 0, stream>>>(gf_part, g1_w, g1_b, bn1_g, bn1_b, ca1_w, ca1_b,
                                    ca2_w, ca2_b, g2_w, g2_b, bn2_g, bn2_b, g3_w, g3_b,
                                    gidx, gwts);
    k3_out<<<1024, 256, 0, stream>>>(feat, s_w, s_b, e_w, e_b, gidx, gwts, out);
}

// Round 2
// 359.046 us; speedup vs baseline: 1.0820x; 1.0820x over previous
//
#include <hip/hip_runtime.h>
#include <hip/hip_bf16.h>
#include <stdint.h>

#define HW 16384

typedef __bf16 bf16_t;
typedef bf16_t bf16x8 __attribute__((ext_vector_type(8)));
typedef float f32x4 __attribute__((ext_vector_type(4)));

// tanh-form GELU via hw exp2 + hw rcp:
// gelu(x) = x * sigmoid(1.5957691*(x + 0.044715 x^3)); 1.5957691*log2(e)=2.3022083
__device__ __forceinline__ float gelu_f(float x) {
    float t = x * fmaf(x * x, 0.044715f, 1.0f);
    float e = __builtin_amdgcn_exp2f(-2.3022083f * t);
    return x * __builtin_amdgcn_rcpf(1.0f + e);
}

__device__ __forceinline__ uint32_t pk2(float a, float b) {
    union { bf16_t h[2]; uint32_t u; } z;
    z.h[0] = (bf16_t)a; z.h[1] = (bf16_t)b;
    return z.u;
}

// async global->LDS, 16B per lane; LDS dest = uniform base + lane*16
__device__ __forceinline__ void load16_to_lds(const float* g, float* lds) {
    __builtin_amdgcn_global_load_lds(
        (const __attribute__((address_space(1))) uint32_t*)g,
        (__attribute__((address_space(3))) uint32_t*)lds, 16, 0, 0);
}

// load 8 consecutive fp32 -> bf16x8 fragment (32B aligned source)
__device__ __forceinline__ bf16x8 frag8(const float* src) {
    float4 lo = ((const float4*)src)[0];
    float4 hi = ((const float4*)src)[1];
    bf16x8 r;
    r[0] = (bf16_t)lo.x; r[1] = (bf16_t)lo.y; r[2] = (bf16_t)lo.z; r[3] = (bf16_t)lo.w;
    r[4] = (bf16_t)hi.x; r[5] = (bf16_t)hi.y; r[6] = (bf16_t)hi.z; r[7] = (bf16_t)hi.w;
    return r;
}

// load 4+4 fp32 (two float4 at different bases) -> bf16x8 fragment
__device__ __forceinline__ bf16x8 frag44(const float* a, const float* b) {
    float4 lo = *(const float4*)a;
    float4 hi = *(const float4*)b;
    bf16x8 r;
    r[0] = (bf16_t)lo.x; r[1] = (bf16_t)lo.y; r[2] = (bf16_t)lo.z; r[3] = (bf16_t)lo.w;
    r[4] = (bf16_t)hi.x; r[5] = (bf16_t)hi.y; r[6] = (bf16_t)hi.z; r[7] = (bf16_t)hi.w;
    return r;
}

// ---------------------------------------------------------------------------
// Kernel 1: features = gelu(fe_w @ x + fe_b) -> bf16 pixel-major (permuted
// channel order cperm = g*16 + ot*4 + r  <->  ch = ot*16 + g*4 + r), + gf
// partials. Depth-3 DMA ring over 64-px tiles:
//   LDS xs[3][64 rows][64 px] fp32 (48 KB), raw s_barrier + counted vmcnt.
// The wait at iter i targets stage S(i+1) issued TWO iterations earlier
// (~1100+ cyc of intervening work > ~900 cyc HBM latency) -> no stall.
// Stores: each lane packs 16 bf16 (32B) covering cperm [g*16, g*16+16);
// a wave instruction writes 16 full 128B feat lines (no write amplification).
// Chunk XOR swizzle on the GLOBAL side keeps ds_read bank-conflict-free.
// Grid: 32 samples * 32 superstripes; block = 4 waves; 8 tiles per block.
// vmcnt ledger (2 stores V(i) per COMPUTE, 4 loads per STAGE):
//   prologue A(16L)+bias(16L) pinned, S0 S1 S2 -> vmcnt(8) retires A,bias,S0.
//   iter0: newer-than-S1 = S2(4)+V0(2)+S3(4) = 10
//   iter1..4: newer-than-S(i+1) = V(i-1)2 + S(i+2)4 + V(i)2 + S(i+3)4 = 12
//   iter5: newer-than-S6 = V4(2)+S7(4)+V5(2) = 8
//   iter6: newer-than-S7 = V5(2)+V6(2) = 4
// ---------------------------------------------------------------------------
__global__ __launch_bounds__(256, 3)
void k1_feat(const float* __restrict__ x, const float* __restrict__ fe_w,
             const float* __restrict__ fe_b, bf16_t* __restrict__ feat,
             float* __restrict__ gf_part) {
    __shared__ float xs[3][64 * 64];   // 48 KB
    __shared__ float gf4[4][64];

    int tid = threadIdx.x;
    int lane = tid & 63;
    int wid = tid >> 6;
    int r16 = lane & 15;
    int g = lane >> 4;
    int b = blockIdx.x >> 5;
    int ss = blockIdx.x & 31;
    int p0 = ss * 512;

    // A fragments (fe_w as MFMA A: row = out-ch = r16, k = kh*32 + g*8 + j)
    bf16x8 A[4][2];
    f32x4 bias[4];
#pragma unroll
    for (int ot = 0; ot < 4; ++ot) {
#pragma unroll
        for (int kh = 0; kh < 2; ++kh)
            A[ot][kh] = frag8(fe_w + (ot * 16 + r16) * 64 + kh * 32 + g * 8);
#pragma unroll
        for (int r = 0; r < 4; ++r) bias[ot][r] = fe_b[ot * 16 + g * 4 + r];
    }
    // pin A/bias loads BEFORE the stage DMAs so the vmcnt ledger holds
    asm volatile("" ::: "memory");

    int j16 = lane & 15;   // 16B chunk within row
    int rsub = lane >> 4;  // row within 4-row group

    auto STAGE = [&](int buf, int i) {
#pragma unroll
        for (int s = 0; s < 4; ++s) {
            int c0 = wid * 16 + s * 4;             // first row of this instr
            int c = c0 + rsub;                     // this lane's row
            int gch = j16 ^ (((c >> 3) & 3) << 2); // pre-swizzled global chunk
            const float* gsrc = x + (size_t)(b * 64 + c) * HW + p0 + i * 64 + gch * 4;
            load16_to_lds(gsrc, &xs[buf][c0 * 64]);  // uniform base per instr
        }
    };

    float gfp[4][4] = {};
    bf16_t* featb = feat + (size_t)b * HW * 64;
    int wb = 16 * (wid ^ g) + r16;                 // swizzled read dword in row

    auto COMPUTE = [&](int buf, int i) {
        bf16x8 B0, B1;
#pragma unroll
        for (int j = 0; j < 8; ++j) {
            B0[j] = (bf16_t)xs[buf][(g * 8 + j) * 64 + wb];
            B1[j] = (bf16_t)xs[buf][(32 + g * 8 + j) * 64 + wb];
        }
        int pg = p0 + i * 64 + wid * 16 + r16;
        float vals[4][4];
#pragma unroll
        for (int ot = 0; ot < 4; ++ot) {
            f32x4 y = {0.f, 0.f, 0.f, 0.f};
            y = __builtin_amdgcn_mfma_f32_16x16x32_bf16(A[ot][0], B0, y, 0, 0, 0);
            y = __builtin_amdgcn_mfma_f32_16x16x32_bf16(A[ot][1], B1, y, 0, 0, 0);
#pragma unroll
            for (int r = 0; r < 4; ++r) {
                float v = gelu_f(y[r] + bias[ot][r]);
                gfp[ot][r] += v;
                vals[ot][r] = v;
            }
        }
        uint4 lo, hi;
        lo.x = pk2(vals[0][0], vals[0][1]); lo.y = pk2(vals[0][2], vals[0][3]);
        lo.z = pk2(vals[1][0], vals[1][1]); lo.w = pk2(vals[1][2], vals[1][3]);
        hi.x = pk2(vals[2][0], vals[2][1]); hi.y = pk2(vals[2][2], vals[2][3]);
        hi.z = pk2(vals[3][0], vals[3][1]); hi.w = pk2(vals[3][2], vals[3][3]);
        uint4* dst = (uint4*)(featb + (size_t)pg * 64 + g * 16);
        dst[0] = lo;                                // cperm g*16 + [0,8)
        dst[1] = hi;                                // cperm g*16 + [8,16)
    };

    // prologue: fill 3 buffers; retire A,bias,S0 (leave S1,S2 = 8 in flight)
    STAGE(0, 0); STAGE(1, 1); STAGE(2, 2);
    asm volatile("s_waitcnt vmcnt(8)" ::: "memory");
    __builtin_amdgcn_s_barrier();

#define K1_STEP(i, buf, VM, ...) \
    COMPUTE(buf, i); \
    asm volatile("s_waitcnt lgkmcnt(0)" ::: "memory"); \
    __builtin_amdgcn_s_barrier(); \
    __VA_ARGS__; \
    asm volatile("s_waitcnt " VM ::: "memory"); \
    __builtin_amdgcn_s_barrier();

    K1_STEP(0, 0, "vmcnt(10)", STAGE(0, 3))
    K1_STEP(1, 1, "vmcnt(12)", STAGE(1, 4))
    K1_STEP(2, 2, "vmcnt(12)", STAGE(2, 5))
    K1_STEP(3, 0, "vmcnt(12)", STAGE(0, 6))
    K1_STEP(4, 1, "vmcnt(12)", STAGE(1, 7))
    K1_STEP(5, 2, "vmcnt(8)")
    K1_STEP(6, 0, "vmcnt(4)")
    COMPUTE(1, 7);
#undef K1_STEP

    // cross-wave gf reduction -> per-block partial (no atomics)
#pragma unroll
    for (int ot = 0; ot < 4; ++ot)
#pragma unroll
        for (int r = 0; r < 4; ++r) {
            float v = gfp[ot][r];
            v += __shfl_xor(v, 1);
            v += __shfl_xor(v, 2);
            v += __shfl_xor(v, 4);
            v += __shfl_xor(v, 8);
            if (r16 == 0) gf4[wid][ot * 16 + g * 4 + r] = v;
        }
    __syncthreads();
    if (tid < 64)
        gf_part[(size_t)blockIdx.x * 64 + tid] =
            gf4[0][tid] + gf4[1][tid] + gf4[2][tid] + gf4[3][tid];
}

// ---------------------------------------------------------------------------
// Kernel 2: gating MLP. One block per sample (grid=32). Reduces k1's 32
// per-superstripe partials, then LDS-staged matvec chain (2-way split chains).
// ---------------------------------------------------------------------------
__global__ __launch_bounds__(256)
void k2_gate(const float* __restrict__ gf_part,
             const float* __restrict__ g1_w, const float* __restrict__ g1_b,
             const float* __restrict__ bn1_g, const float* __restrict__ bn1_b,
             const float* __restrict__ ca1_w, const float* __restrict__ ca1_b,
             const float* __restrict__ ca2_w, const float* __restrict__ ca2_b,
             const float* __restrict__ g2_w, const float* __restrict__ g2_b,
             const float* __restrict__ bn2_g, const float* __restrict__ bn2_b,
             const float* __restrict__ g3_w, const float* __restrict__ g3_b,
             int* __restrict__ gidx, float* __restrict__ gw) {
    __shared__ float w1t[128 * 65];    // g1_w padded
    __shared__ float wc1[8 * 129];     // ca1_w padded
    __shared__ float wc2[128 * 9];     // ca2_w padded
    __shared__ float w2t[64 * 129];    // g2_w padded
    __shared__ float w3[8 * 65];       // g3_w padded
    __shared__ float gf[64], h1[128], a1[8], hh[64], sc[8];
    const float R1 = 0.99999500003749969f;   // 1/sqrt(1+1e-5)
    int tid = threadIdx.x;
    int b = blockIdx.x;

    // stage weights: coalesced float4 global loads -> padded LDS rows
    for (int i = tid; i < 2048; i += 256) {        // g1_w [128][64]
        float4 v = ((const float4*)g1_w)[i];
        float* d = w1t + (i >> 4) * 65 + (i & 15) * 4;
        d[0] = v.x; d[1] = v.y; d[2] = v.z; d[3] = v.w;
    }
    for (int i = tid; i < 2048; i += 256) {        // g2_w [64][128]
        float4 v = ((const float4*)g2_w)[i];
        float* d = w2t + (i >> 5) * 129 + (i & 31) * 4;
        d[0] = v.x; d[1] = v.y; d[2] = v.z; d[3] = v.w;
    }
    if (tid < 256) {                               // ca1_w [8][128]
        int i = tid;
        float4 v = ((const float4*)ca1_w)[i];
        float* d = wc1 + (i >> 5) * 129 + (i & 31) * 4;
        d[0] = v.x; d[1] = v.y; d[2] = v.z; d[3] = v.w;
    }
    if (tid < 256) {                               // ca2_w [128][8]
        int i = tid;
        float4 v = ((const float4*)ca2_w)[i];
        float* d = wc2 + (i >> 1) * 9 + (i & 1) * 4;
        d[0] = v.x; d[1] = v.y; d[2] = v.z; d[3] = v.w;
    }
    if (tid < 128) {                               // g3_w [8][64]
        int i = tid;
        float4 v = ((const float4*)g3_w)[i];
        float* d = w3 + (i >> 4) * 65 + (i & 15) * 4;
        d[0] = v.x; d[1] = v.y; d[2] = v.z; d[3] = v.w;
    }
    if (tid < 64) {                                // reduce k1 partials
        float s0 = 0.f, s1 = 0.f;
#pragma unroll
        for (int ssi = 0; ssi < 32; ssi += 2) {
            s0 += gf_part[(size_t)(b * 32 + ssi) * 64 + tid];
            s1 += gf_part[(size_t)(b * 32 + ssi + 1) * 64 + tid];
        }
        gf[tid] = (s0 + s1) * (1.0f / 16384.0f);
    }
    __syncthreads();

    if (tid < 128) {                 // h1 = gelu(bn(g1))
        int j = tid;
        float s0 = 0.f, s1 = 0.f;
#pragma unroll 8
        for (int c = 0; c < 64; c += 2) {
            s0 += gf[c] * w1t[j * 65 + c];
            s1 += gf[c + 1] * w1t[j * 65 + c + 1];
        }
        float s = g1_b[j] + s0 + s1;
        s = s * (bn1_g[j] * R1) + bn1_b[j];
        h1[j] = gelu_f(s);
    }
    __syncthreads();
    if (tid < 8) {                   // a1 = gelu(ca1)
        int j = tid;
        float s0 = 0.f, s1 = 0.f;
#pragma unroll 8
        for (int c = 0; c < 128; c += 2) {
            s0 += h1[c] * wc1[j * 129 + c];
            s1 += h1[c + 1] * wc1[j * 129 + c + 1];
        }
        a1[j] = gelu_f(ca1_b[j] + s0 + s1);
    }
    __syncthreads();
    if (tid < 128) {                 // h1 *= sigmoid(2*att)
        int j = tid;
        float s = ca2_b[j];
#pragma unroll
        for (int r = 0; r < 8; ++r) s += a1[r] * wc2[j * 9 + r];
        float e2 = __builtin_amdgcn_exp2f(-2.8853901f * s);  // 2*log2(e)
        h1[j] = h1[j] * __builtin_amdgcn_rcpf(1.0f + e2);
    }
    __syncthreads();
    if (tid < 64) {                  // hh = gelu(bn(g2))
        int j = tid;
        float s0 = 0.f, s1 = 0.f;
#pragma unroll 8
        for (int c = 0; c < 128; c += 2) {
            s0 += h1[c] * w2t[j * 129 + c];
            s1 += h1[c + 1] * w2t[j * 129 + c + 1];
        }
        float s = g2_b[j] + s0 + s1;
        s = s * (bn2_g[j] * R1) + bn2_b[j];
        hh[j] = gelu_f(s);
    }
    __syncthreads();
    if (tid < 8) {                   // scores
        int j = tid;
        float s0 = 0.f, s1 = 0.f;
#pragma unroll 8
        for (int c = 0; c < 64; c += 2) {
            s0 += hh[c] * w3[j * 65 + c];
            s1 += hh[c + 1] * w3[j * 65 + c + 1];
        }
        sc[j] = g3_b[j] + s0 + s1;
    }
    __syncthreads();
    if (tid == 0) {
        float v0 = -1e30f, v1 = -1e30f;
        int i0 = 0, i1 = 0;
#pragma unroll
        for (int e = 0; e < 8; ++e) {
            float s = sc[e];
            if (s > v0) { v1 = v0; i1 = i0; v0 = s; i0 = e; }
            else if (s > v1) { v1 = s; i1 = e; }
        }
        float t = __builtin_amdgcn_exp2f(0.7213475f * (v1 - v0));  // 0.5*log2(e)
        float den = __builtin_amdgcn_rcpf(1.0f + t);
        gidx[b * 2] = i0; gidx[b * 2 + 1] = i1;
        gw[b * 2] = den; gw[b * 2 + 1] = t * den;
    }
}

// ---------------------------------------------------------------------------
// Kernel 3: out = 0.5*(gelu(s0)+gelu(s1)) + w0*gelu(e[i0]) + w1*gelu(e[i1]).
// Operand-swapped MFMA: A = feat pixels (row=px=r16, k=cperm), B = weight
// fragment (col=out-ch=r16, k=cperm) -> D row = px = g*4+r, col = out-ch.
// feat's channel order is PERMUTED (cperm = G*16+ot*4+r <-> ch = ot*16+G*4+r);
// weight fragments apply the same k-permutation: element j of frag (g,kh)
// must be W[row][ch(cperm = kh*32+g*8+j)]:
//   ch = ((g&1)*2 + (j>>2))*16 + (kh*2 + (g>>1))*4 + (j&3)
// i.e. j=0..3 at base, j=4..7 at base+16, base = (g&1)*32 + (kh*2+(g>>1))*4.
// Each lane owns 4 CONSECUTIVE pixels of one channel -> float4 stores.
// ---------------------------------------------------------------------------
__global__ __launch_bounds__(256, 4)
void k3_out(const bf16_t* __restrict__ feat, const float* __restrict__ s_w,
            const float* __restrict__ s_b, const float* __restrict__ e_w,
            const float* __restrict__ e_b, const int* __restrict__ gidx,
            const float* __restrict__ gw, float* __restrict__ out) {
    int tid = threadIdx.x;
    int lane = tid & 63, wid = tid >> 6;
    int r16 = lane & 15, g = lane >> 4;
    int b = blockIdx.x >> 5;
    int stripe = blockIdx.x & 31;

    int i0 = gidx[2 * b], i1 = gidx[2 * b + 1];
    float coef[4] = {0.5f, 0.5f, gw[2 * b], gw[2 * b + 1]};
    const float* Wm[4] = {s_w, s_w + 4096,
                          e_w + (size_t)i0 * 4096, e_w + (size_t)i1 * 4096};
    const float* Bv[4] = {s_b, s_b + 64, e_b + i0 * 64, e_b + i1 * 64};

    bf16x8 Wf[4][2];
    float bias[4];
    int row = wid * 16 + r16;                      // this lane's out-channel
#pragma unroll
    for (int m = 0; m < 4; ++m) {
#pragma unroll
        for (int kh = 0; kh < 2; ++kh) {
            int base = (g & 1) * 32 + (kh * 2 + (g >> 1)) * 4;
            Wf[m][kh] = frag44(Wm[m] + row * 64 + base,
                               Wm[m] + row * 64 + base + 16);
        }
        bias[m] = Bv[m][row];
    }

    const uint4* fb = (const uint4*)(feat + (size_t)b * HW * 64);
    float* outb = out + ((size_t)b * 64 + row) * HW + stripe * 512;
    int pbase = stripe * 512 + r16;

    auto BODY = [&](int t, uint4 u0, uint4 u1) {
        bf16x8 F0 = __builtin_bit_cast(bf16x8, u0);
        bf16x8 F1 = __builtin_bit_cast(bf16x8, u1);
        f32x4 acc = {0.f, 0.f, 0.f, 0.f};
#pragma unroll
        for (int m = 0; m < 4; ++m) {
            f32x4 y = {0.f, 0.f, 0.f, 0.f};
            y = __builtin_amdgcn_mfma_f32_16x16x32_bf16(F0, Wf[m][0], y, 0, 0, 0);
            y = __builtin_amdgcn_mfma_f32_16x16x32_bf16(F1, Wf[m][1], y, 0, 0, 0);
#pragma unroll
            for (int r = 0; r < 4; ++r)
                acc[r] += coef[m] * gelu_f(y[r] + bias[m]);
        }
        float4 st = {acc[0], acc[1], acc[2], acc[3]};
        *(float4*)(outb + t * 16 + g * 4) = st;     // 4 consecutive pixels
    };

    uint4 u0 = fb[(size_t)pbase * 8 + g];
    uint4 u1 = fb[(size_t)pbase * 8 + 4 + g];
#pragma unroll 4
    for (int t = 0; t < 31; ++t) {
        uint4 n0 = fb[(size_t)(pbase + (t + 1) * 16) * 8 + g];
        uint4 n1 = fb[(size_t)(pbase + (t + 1) * 16) * 8 + 4 + g];
        BODY(t, u0, u1);
        u0 = n0; u1 = n1;
    }
    BODY(31, u0, u1);
}

extern "C" void kernel_launch(void* const* d_in, const int* in_sizes, int n_in,
                              void* d_out, int out_size, void* d_ws, size_t ws_size,
                              hipStream_t stream) {
    (void)in_sizes; (void)n_in; (void)out_size; (void)ws_size;
    const float* x     = (const float*)d_in[0];
    const float* fe_w  = (const float*)d_in[1];
    const float* fe_b  = (const float*)d_in[2];
    const float* s_w   = (const float*)d_in[3];
    const float* s_b   = (const float*)d_in[4];
    const float* e_w   = (const float*)d_in[5];
    const float* e_b   = (const float*)d_in[6];
    const float* g1_w  = (const float*)d_in[7];
    const float* g1_b  = (const float*)d_in[8];
    const float* bn1_g = (const float*)d_in[9];
    const float* bn1_b = (const float*)d_in[10];
    const float* ca1_w = (const float*)d_in[11];
    const float* ca1_b = (const float*)d_in[12];
    const float* ca2_w = (const float*)d_in[13];
    const float* ca2_b = (const float*)d_in[14];
    const float* g2_w  = (const float*)d_in[15];
    const float* g2_b  = (const float*)d_in[16];
    const float* bn2_g = (const float*)d_in[17];
    const float* bn2_b = (const float*)d_in[18];
    const float* g3_w  = (const float*)d_in[19];
    const float* g3_b  = (const float*)d_in[20];
    float* out = (float*)d_out;

    char* wsb = (char*)d_ws;
    bf16_t* feat   = (bf16_t*)wsb;                           // 64 MiB bf16 features
    float* gf_part = (float*)(wsb + 67108864);               // 256 KiB partials
    int* gidx      = (int*)(wsb + 67108864 + 262144);        // 256 B
    float* gwts    = (float*)(wsb + 67108864 + 262144 + 256);// 256 B

    k1_feat<<<1024, 256, 0, stream>>>(x, fe_w, fe_b, feat, gf_part);
    k2_gate<<<32, 256, 0, stream>>>(gf_part, g1_w, g1_b, bn1_g, bn1_b, ca1_w, ca1_b,
                                    ca2_w, ca2_b, g2_w, g2_b, bn2_g, bn2_b, g3_w, g3_b,
                                    gidx, gwts);
    k3_out<<<1024, 256, 0, stream>>>(feat, s_w, s_b, e_w, e_b, gidx, gwts, out);
}

// Round 3
// 343.026 us; speedup vs baseline: 1.1325x; 1.0467x over previous
//
#include <hip/hip_runtime.h>
#include <hip/hip_bf16.h>
#include <stdint.h>

#define HW 16384

typedef __bf16 bf16_t;
typedef bf16_t bf16x8 __attribute__((ext_vector_type(8)));
typedef float f32x4 __attribute__((ext_vector_type(4)));

// tanh-form GELU via hw exp2 + hw rcp:
// gelu(x) = x * sigmoid(1.5957691*(x + 0.044715 x^3)); 1.5957691*log2(e)=2.3022083
__device__ __forceinline__ float gelu_f(float x) {
    float t = x * fmaf(x * x, 0.044715f, 1.0f);
    float e = __builtin_amdgcn_exp2f(-2.3022083f * t);
    return x * __builtin_amdgcn_rcpf(1.0f + e);
}

__device__ __forceinline__ uint32_t pk2(float a, float b) {
    union { bf16_t h[2]; uint32_t u; } z;
    z.h[0] = (bf16_t)a; z.h[1] = (bf16_t)b;
    return z.u;
}

// async global->LDS, 16B per lane; LDS dest = uniform base + lane*16
__device__ __forceinline__ void load16_to_lds(const float* g, float* lds) {
    __builtin_amdgcn_global_load_lds(
        (const __attribute__((address_space(1))) uint32_t*)g,
        (__attribute__((address_space(3))) uint32_t*)lds, 16, 0, 0);
}

// load 8 consecutive fp32 -> bf16x8 fragment (32B aligned source)
__device__ __forceinline__ bf16x8 frag8(const float* src) {
    float4 lo = ((const float4*)src)[0];
    float4 hi = ((const float4*)src)[1];
    bf16x8 r;
    r[0] = (bf16_t)lo.x; r[1] = (bf16_t)lo.y; r[2] = (bf16_t)lo.z; r[3] = (bf16_t)lo.w;
    r[4] = (bf16_t)hi.x; r[5] = (bf16_t)hi.y; r[6] = (bf16_t)hi.z; r[7] = (bf16_t)hi.w;
    return r;
}

// load 4+4 fp32 (two float4 at different bases) -> bf16x8 fragment
__device__ __forceinline__ bf16x8 frag44(const float* a, const float* b) {
    float4 lo = *(const float4*)a;
    float4 hi = *(const float4*)b;
    bf16x8 r;
    r[0] = (bf16_t)lo.x; r[1] = (bf16_t)lo.y; r[2] = (bf16_t)lo.z; r[3] = (bf16_t)lo.w;
    r[4] = (bf16_t)hi.x; r[5] = (bf16_t)hi.y; r[6] = (bf16_t)hi.z; r[7] = (bf16_t)hi.w;
    return r;
}

// ---------------------------------------------------------------------------
// Kernel 1: features = gelu(fe_w @ x + fe_b) -> bf16 pixel-major (permuted
// channel order cperm = g*16 + ot*4 + r  <->  ch = ot*16 + g*4 + r), + gf
// partials.  WAVE-PRIVATE tiles, ZERO barriers in the hot path:
//   each wave owns one 64ch x 32px tile (8 KB fp32 LDS), stages it with 8
//   global_load_lds (1 KB each), waits only its OWN vmcnt (4 then 0), and
//   computes.  16 independent waves/CU -> latency hidden by pure TLP.
// Chunk swizzle (applied to the GLOBAL source address per 16B chunk):
//   DMA instr s (rows s*8..s*8+7): lane l fetches global chunk (l&7)^((s&3)<<1)
//   reader: element (row,col) at dword row*32 + ((col>>2)^(g<<1))*4 + (col&3)
//   where g=(row>>3)&3 -> only 2-way bank aliasing (free).
// Grid: 16384 tiles = 4096 blocks * 4 waves; one __syncthreads at the end
// for the per-block gf partial.
// ---------------------------------------------------------------------------
__global__ __launch_bounds__(256, 4)
void k1_feat(const float* __restrict__ x, const float* __restrict__ fe_w,
             const float* __restrict__ fe_b, bf16_t* __restrict__ feat,
             float* __restrict__ gf_part) {
    __shared__ float xs[4][32 * 64];   // 8 KB per wave, 32 KB total
    __shared__ float gf4[4][64];

    int tid = threadIdx.x;
    int lane = tid & 63;
    int wid = tid >> 6;
    int r16 = lane & 15;
    int g = lane >> 4;
    int gtile = blockIdx.x * 4 + wid;       // 16384 tiles of 32 px
    int b = gtile >> 9;                     // 512 tiles per sample
    int p0 = (gtile & 511) * 32;

    // A fragments (fe_w as MFMA A: row = out-ch = r16, k = kh*32 + g*8 + j)
    bf16x8 A[4][2];
    f32x4 bias[4];
#pragma unroll
    for (int ot = 0; ot < 4; ++ot) {
#pragma unroll
        for (int kh = 0; kh < 2; ++kh)
            A[ot][kh] = frag8(fe_w + (ot * 16 + r16) * 64 + kh * 32 + g * 8);
#pragma unroll
        for (int r = 0; r < 4; ++r) bias[ot][r] = fe_b[ot * 16 + g * 4 + r];
    }
    // pin A/bias loads BEFORE the DMA so the per-wave vmcnt ledger holds
    asm volatile("" ::: "memory");

    float* xw = &xs[wid][0];
    {
        int rl = lane >> 3;                 // row within 8-row group
        int ch0 = lane & 7;                 // 16B chunk (LDS-linear position)
#pragma unroll
        for (int s = 0; s < 8; ++s) {
            int row = s * 8 + rl;
            int gch = ch0 ^ ((s & 3) << 1); // pre-swizzled global chunk
            const float* gsrc = x + (size_t)(b * 64 + row) * HW + p0 + gch * 4;
            load16_to_lds(gsrc, xw + s * 256);   // uniform base per instr
        }
    }

    // swizzled column offsets for the two 16-px windows (a = 0, 1)
    int cm0 = ((((r16 >> 2) + 0) ^ (g << 1)) << 2) + (r16 & 3);
    int cm1 = ((((r16 >> 2) + 4) ^ (g << 1)) << 2) + (r16 & 3);

    float gfp[4][4] = {};
    bf16_t* featb = feat + (size_t)b * HW * 64;

    // rows 0..31 ready (A/bias + DMA s=0..3 retired; 4 newest outstanding)
    asm volatile("s_waitcnt vmcnt(4)" ::: "memory");

    f32x4 y0[4], y1[4];
    {
        bf16x8 B00, B10;
#pragma unroll
        for (int j = 0; j < 8; ++j) {
            int ro = (g * 8 + j) * 32;
            B00[j] = (bf16_t)xw[ro + cm0];
            B10[j] = (bf16_t)xw[ro + cm1];
        }
#pragma unroll
        for (int ot = 0; ot < 4; ++ot) {
            f32x4 z = {0.f, 0.f, 0.f, 0.f};
            y0[ot] = __builtin_amdgcn_mfma_f32_16x16x32_bf16(A[ot][0], B00, z, 0, 0, 0);
            y1[ot] = __builtin_amdgcn_mfma_f32_16x16x32_bf16(A[ot][0], B10, z, 0, 0, 0);
        }
    }
    // rows 32..63 ready
    asm volatile("s_waitcnt vmcnt(0)" ::: "memory");
    {
        bf16x8 B01, B11;
#pragma unroll
        for (int j = 0; j < 8; ++j) {
            int ro = (32 + g * 8 + j) * 32;
            B01[j] = (bf16_t)xw[ro + cm0];
            B11[j] = (bf16_t)xw[ro + cm1];
        }
#pragma unroll
        for (int ot = 0; ot < 4; ++ot) {
            y0[ot] = __builtin_amdgcn_mfma_f32_16x16x32_bf16(A[ot][1], B01, y0[ot], 0, 0, 0);
            y1[ot] = __builtin_amdgcn_mfma_f32_16x16x32_bf16(A[ot][1], B11, y1[ot], 0, 0, 0);
        }
    }

    // epilogue per 16-px window: gelu, gf accumulate, full-line bf16 stores
#pragma unroll
    for (int a = 0; a < 2; ++a) {
        f32x4* y = a ? y1 : y0;
        float vals[4][4];
#pragma unroll
        for (int ot = 0; ot < 4; ++ot)
#pragma unroll
            for (int r = 0; r < 4; ++r) {
                float v = gelu_f(y[ot][r] + bias[ot][r]);
                gfp[ot][r] += v;
                vals[ot][r] = v;
            }
        uint4 lo, hi;
        lo.x = pk2(vals[0][0], vals[0][1]); lo.y = pk2(vals[0][2], vals[0][3]);
        lo.z = pk2(vals[1][0], vals[1][1]); lo.w = pk2(vals[1][2], vals[1][3]);
        hi.x = pk2(vals[2][0], vals[2][1]); hi.y = pk2(vals[2][2], vals[2][3]);
        hi.z = pk2(vals[3][0], vals[3][1]); hi.w = pk2(vals[3][2], vals[3][3]);
        int px = p0 + a * 16 + r16;
        uint4* dst = (uint4*)(featb + (size_t)px * 64 + g * 16);
        dst[0] = lo;                        // cperm g*16 + [0,8)
        dst[1] = hi;                        // cperm g*16 + [8,16)
    }

    // cross-wave gf reduction -> per-block partial (one sync, end of block)
#pragma unroll
    for (int ot = 0; ot < 4; ++ot)
#pragma unroll
        for (int r = 0; r < 4; ++r) {
            float v = gfp[ot][r];
            v += __shfl_xor(v, 1);
            v += __shfl_xor(v, 2);
            v += __shfl_xor(v, 4);
            v += __shfl_xor(v, 8);
            if (r16 == 0) gf4[wid][ot * 16 + g * 4 + r] = v;
        }
    __syncthreads();
    if (tid < 64)
        gf_part[(size_t)blockIdx.x * 64 + tid] =
            gf4[0][tid] + gf4[1][tid] + gf4[2][tid] + gf4[3][tid];
}

// ---------------------------------------------------------------------------
// Kernel 2: gating MLP. One block per sample (grid=32). Reduces k1's 128
// per-block partials, then LDS-staged matvec chain (2-way split chains).
// ---------------------------------------------------------------------------
__global__ __launch_bounds__(256)
void k2_gate(const float* __restrict__ gf_part,
             const float* __restrict__ g1_w, const float* __restrict__ g1_b,
             const float* __restrict__ bn1_g, const float* __restrict__ bn1_b,
             const float* __restrict__ ca1_w, const float* __restrict__ ca1_b,
             const float* __restrict__ ca2_w, const float* __restrict__ ca2_b,
             const float* __restrict__ g2_w, const float* __restrict__ g2_b,
             const float* __restrict__ bn2_g, const float* __restrict__ bn2_b,
             const float* __restrict__ g3_w, const float* __restrict__ g3_b,
             int* __restrict__ gidx, float* __restrict__ gw) {
    __shared__ float w1t[128 * 65];    // g1_w padded
    __shared__ float wc1[8 * 129];     // ca1_w padded
    __shared__ float wc2[128 * 9];     // ca2_w padded
    __shared__ float w2t[64 * 129];    // g2_w padded
    __shared__ float w3[8 * 65];       // g3_w padded
    __shared__ float gf[64], h1[128], a1[8], hh[64], sc[8];
    const float R1 = 0.99999500003749969f;   // 1/sqrt(1+1e-5)
    int tid = threadIdx.x;
    int b = blockIdx.x;

    // stage weights: coalesced float4 global loads -> padded LDS rows
    for (int i = tid; i < 2048; i += 256) {        // g1_w [128][64]
        float4 v = ((const float4*)g1_w)[i];
        float* d = w1t + (i >> 4) * 65 + (i & 15) * 4;
        d[0] = v.x; d[1] = v.y; d[2] = v.z; d[3] = v.w;
    }
    for (int i = tid; i < 2048; i += 256) {        // g2_w [64][128]
        float4 v = ((const float4*)g2_w)[i];
        float* d = w2t + (i >> 5) * 129 + (i & 31) * 4;
        d[0] = v.x; d[1] = v.y; d[2] = v.z; d[3] = v.w;
    }
    if (tid < 256) {                               // ca1_w [8][128]
        int i = tid;
        float4 v = ((const float4*)ca1_w)[i];
        float* d = wc1 + (i >> 5) * 129 + (i & 31) * 4;
        d[0] = v.x; d[1] = v.y; d[2] = v.z; d[3] = v.w;
    }
    if (tid < 256) {                               // ca2_w [128][8]
        int i = tid;
        float4 v = ((const float4*)ca2_w)[i];
        float* d = wc2 + (i >> 1) * 9 + (i & 1) * 4;
        d[0] = v.x; d[1] = v.y; d[2] = v.z; d[3] = v.w;
    }
    if (tid < 128) {                               // g3_w [8][64]
        int i = tid;
        float4 v = ((const float4*)g3_w)[i];
        float* d = w3 + (i >> 4) * 65 + (i & 15) * 4;
        d[0] = v.x; d[1] = v.y; d[2] = v.z; d[3] = v.w;
    }
    if (tid < 64) {                                // reduce k1 partials (128)
        float s0 = 0.f, s1 = 0.f, s2 = 0.f, s3 = 0.f;
        const float* gp = gf_part + (size_t)b * 128 * 64 + tid;
#pragma unroll 8
        for (int i = 0; i < 128; i += 4) {
            s0 += gp[(size_t)(i + 0) * 64];
            s1 += gp[(size_t)(i + 1) * 64];
            s2 += gp[(size_t)(i + 2) * 64];
            s3 += gp[(size_t)(i + 3) * 64];
        }
        gf[tid] = ((s0 + s1) + (s2 + s3)) * (1.0f / 16384.0f);
    }
    __syncthreads();

    if (tid < 128) {                 // h1 = gelu(bn(g1))
        int j = tid;
        float s0 = 0.f, s1 = 0.f;
#pragma unroll 8
        for (int c = 0; c < 64; c += 2) {
            s0 += gf[c] * w1t[j * 65 + c];
            s1 += gf[c + 1] * w1t[j * 65 + c + 1];
        }
        float s = g1_b[j] + s0 + s1;
        s = s * (bn1_g[j] * R1) + bn1_b[j];
        h1[j] = gelu_f(s);
    }
    __syncthreads();
    if (tid < 8) {                   // a1 = gelu(ca1)
        int j = tid;
        float s0 = 0.f, s1 = 0.f;
#pragma unroll 8
        for (int c = 0; c < 128; c += 2) {
            s0 += h1[c] * wc1[j * 129 + c];
            s1 += h1[c + 1] * wc1[j * 129 + c + 1];
        }
        a1[j] = gelu_f(ca1_b[j] + s0 + s1);
    }
    __syncthreads();
    if (tid < 128) {                 // h1 *= sigmoid(2*att)
        int j = tid;
        float s = ca2_b[j];
#pragma unroll
        for (int r = 0; r < 8; ++r) s += a1[r] * wc2[j * 9 + r];
        float e2 = __builtin_amdgcn_exp2f(-2.8853901f * s);  // 2*log2(e)
        h1[j] = h1[j] * __builtin_amdgcn_rcpf(1.0f + e2);
    }
    __syncthreads();
    if (tid < 64) {                  // hh = gelu(bn(g2))
        int j = tid;
        float s0 = 0.f, s1 = 0.f;
#pragma unroll 8
        for (int c = 0; c < 128; c += 2) {
            s0 += h1[c] * w2t[j * 129 + c];
            s1 += h1[c + 1] * w2t[j * 129 + c + 1];
        }
        float s = g2_b[j] + s0 + s1;
        s = s * (bn2_g[j] * R1) + bn2_b[j];
        hh[j] = gelu_f(s);
    }
    __syncthreads();
    if (tid < 8) {                   // scores
        int j = tid;
        float s0 = 0.f, s1 = 0.f;
#pragma unroll 8
        for (int c = 0; c < 64; c += 2) {
            s0 += hh[c] * w3[j * 65 + c];
            s1 += hh[c + 1] * w3[j * 65 + c + 1];
        }
        sc[j] = g3_b[j] + s0 + s1;
    }
    __syncthreads();
    if (tid == 0) {
        float v0 = -1e30f, v1 = -1e30f;
        int i0 = 0, i1 = 0;
#pragma unroll
        for (int e = 0; e < 8; ++e) {
            float s = sc[e];
            if (s > v0) { v1 = v0; i1 = i0; v0 = s; i0 = e; }
            else if (s > v1) { v1 = s; i1 = e; }
        }
        float t = __builtin_amdgcn_exp2f(0.7213475f * (v1 - v0));  // 0.5*log2(e)
        float den = __builtin_amdgcn_rcpf(1.0f + t);
        gidx[b * 2] = i0; gidx[b * 2 + 1] = i1;
        gw[b * 2] = den; gw[b * 2 + 1] = t * den;
    }
}

// ---------------------------------------------------------------------------
// Kernel 3: out = 0.5*(gelu(s0)+gelu(s1)) + w0*gelu(e[i0]) + w1*gelu(e[i1]).
// Operand-swapped MFMA: A = feat pixels (row=px=r16, k=cperm), B = weight
// fragment (col=out-ch=r16, k=cperm) -> D row = px = g*4+r, col = out-ch.
// feat's channel order is PERMUTED (cperm = G*16+ot*4+r <-> ch = ot*16+G*4+r);
// weight fragments apply the same k-permutation: j=0..3 at base, j=4..7 at
// base+16, base = (g&1)*32 + (kh*2+(g>>1))*4.
// Each lane owns 4 CONSECUTIVE pixels of one channel -> float4 stores.
// 2048 blocks (64 stripes of 256 px), depth-2 register prefetch.
// ---------------------------------------------------------------------------
__global__ __launch_bounds__(256, 4)
void k3_out(const bf16_t* __restrict__ feat, const float* __restrict__ s_w,
            const float* __restrict__ s_b, const float* __restrict__ e_w,
            const float* __restrict__ e_b, const int* __restrict__ gidx,
            const float* __restrict__ gw, float* __restrict__ out) {
    int tid = threadIdx.x;
    int lane = tid & 63, wid = tid >> 6;
    int r16 = lane & 15, g = lane >> 4;
    int b = blockIdx.x >> 6;
    int stripe = blockIdx.x & 63;

    int i0 = gidx[2 * b], i1 = gidx[2 * b + 1];
    float coef[4] = {0.5f, 0.5f, gw[2 * b], gw[2 * b + 1]};
    const float* Wm[4] = {s_w, s_w + 4096,
                          e_w + (size_t)i0 * 4096, e_w + (size_t)i1 * 4096};
    const float* Bv[4] = {s_b, s_b + 64, e_b + i0 * 64, e_b + i1 * 64};

    bf16x8 Wf[4][2];
    float bias[4];
    int row = wid * 16 + r16;                      // this lane's out-channel
#pragma unroll
    for (int m = 0; m < 4; ++m) {
#pragma unroll
        for (int kh = 0; kh < 2; ++kh) {
            int base = (g & 1) * 32 + (kh * 2 + (g >> 1)) * 4;
            Wf[m][kh] = frag44(Wm[m] + row * 64 + base,
                               Wm[m] + row * 64 + base + 16);
        }
        bias[m] = Bv[m][row];
    }

    const uint4* fb = (const uint4*)(feat + (size_t)b * HW * 64);
    float* outb = out + ((size_t)b * 64 + row) * HW + stripe * 256;
    int pbase = stripe * 256 + r16;

    auto BODY = [&](int t, uint4 u0, uint4 u1) {
        bf16x8 F0 = __builtin_bit_cast(bf16x8, u0);
        bf16x8 F1 = __builtin_bit_cast(bf16x8, u1);
        f32x4 acc = {0.f, 0.f, 0.f, 0.f};
#pragma unroll
        for (int m = 0; m < 4; ++m) {
            f32x4 y = {0.f, 0.f, 0.f, 0.f};
            y = __builtin_amdgcn_mfma_f32_16x16x32_bf16(F0, Wf[m][0], y, 0, 0, 0);
            y = __builtin_amdgcn_mfma_f32_16x16x32_bf16(F1, Wf[m][1], y, 0, 0, 0);
#pragma unroll
            for (int r = 0; r < 4; ++r)
                acc[r] += coef[m] * gelu_f(y[r] + bias[m]);
        }
        float4 st = {acc[0], acc[1], acc[2], acc[3]};
        *(float4*)(outb + t * 16 + g * 4) = st;     // 4 consecutive pixels
    };

    uint4 a0 = fb[(size_t)pbase * 8 + g];
    uint4 a1 = fb[(size_t)pbase * 8 + 4 + g];
    uint4 b0 = fb[(size_t)(pbase + 16) * 8 + g];
    uint4 b1 = fb[(size_t)(pbase + 16) * 8 + 4 + g];
#pragma unroll
    for (int t = 0; t < 14; t += 2) {
        uint4 n0 = fb[(size_t)(pbase + (t + 2) * 16) * 8 + g];
        uint4 n1 = fb[(size_t)(pbase + (t + 2) * 16) * 8 + 4 + g];
        BODY(t, a0, a1); a0 = n0; a1 = n1;
        uint4 m0 = fb[(size_t)(pbase + (t + 3) * 16) * 8 + g];
        uint4 m1 = fb[(size_t)(pbase + (t + 3) * 16) * 8 + 4 + g];
        BODY(t + 1, b0, b1); b0 = m0; b1 = m1;
    }
    BODY(14, a0, a1);
    BODY(15, b0, b1);
}

extern "C" void kernel_launch(void* const* d_in, const int* in_sizes, int n_in,
                              void* d_out, int out_size, void* d_ws, size_t ws_size,
                              hipStream_t stream) {
    (void)in_sizes; (void)n_in; (void)out_size; (void)ws_size;
    const float* x     = (const float*)d_in[0];
    const float* fe_w  = (const float*)d_in[1];
    const float* fe_b  = (const float*)d_in[2];
    const float* s_w   = (const float*)d_in[3];
    const float* s_b   = (const float*)d_in[4];
    const float* e_w   = (const float*)d_in[5];
    const float* e_b   = (const float*)d_in[6];
    const float* g1_w  = (const float*)d_in[7];
    const float* g1_b  = (const float*)d_in[8];
    const float* bn1_g = (const float*)d_in[9];
    const float* bn1_b = (const float*)d_in[10];
    const float* ca1_w = (const float*)d_in[11];
    const float* ca1_b = (const float*)d_in[12];
    const float* ca2_w = (const float*)d_in[13];
    const float* ca2_b = (const float*)d_in[14];
    const float* g2_w  = (const float*)d_in[15];
    const float* g2_b  = (const float*)d_in[16];
    const float* bn2_g = (const float*)d_in[17];
    const float* bn2_b = (const float*)d_in[18];
    const float* g3_w  = (const float*)d_in[19];
    const float* g3_b  = (const float*)d_in[20];
    float* out = (float*)d_out;

    char* wsb = (char*)d_ws;
    bf16_t* feat   = (bf16_t*)wsb;                            // 64 MiB bf16 features
    float* gf_part = (float*)(wsb + 67108864);                // 1 MiB partials
    int* gidx      = (int*)(wsb + 67108864 + 1048576);        // 256 B
    float* gwts    = (float*)(wsb + 67108864 + 1048576 + 256);// 256 B

    k1_feat<<<4096, 256, 0, stream>>>(x, fe_w, fe_b, feat, gf_part);
    k2_gate<<<32, 256, 0, stream>>>(gf_part, g1_w, g1_b, bn1_g, bn1_b, ca1_w, ca1_b,
                                    ca2_w, ca2_b, g2_w, g2_b, bn2_g, bn2_b, g3_w, g3_b,
                                    gidx, gwts);
    k3_out<<<2048, 256, 0, stream>>>(feat, s_w, s_b, e_w, e_b, gidx, gwts, out);
}

// Round 4
// 342.203 us; speedup vs baseline: 1.1352x; 1.0024x over previous
//
#include <hip/hip_runtime.h>
#include <hip/hip_bf16.h>
#include <stdint.h>

#define HW 16384

typedef __bf16 bf16_t;
typedef bf16_t bf16x8 __attribute__((ext_vector_type(8)));
typedef float f32x4 __attribute__((ext_vector_type(4)));

// tanh-form GELU via hw exp2 + hw rcp:
// gelu(x) = x * sigmoid(1.5957691*(x + 0.044715 x^3)); 1.5957691*log2(e)=2.3022083
__device__ __forceinline__ float gelu_f(float x) {
    float t = x * fmaf(x * x, 0.044715f, 1.0f);
    float e = __builtin_amdgcn_exp2f(-2.3022083f * t);
    return x * __builtin_amdgcn_rcpf(1.0f + e);
}

__device__ __forceinline__ uint32_t pk2(float a, float b) {
    union { bf16_t h[2]; uint32_t u; } z;
    z.h[0] = (bf16_t)a; z.h[1] = (bf16_t)b;
    return z.u;
}

// async global->LDS, 16B per lane; LDS dest = uniform base + lane*16
__device__ __forceinline__ void load16_to_lds(const float* g, float* lds) {
    __builtin_amdgcn_global_load_lds(
        (const __attribute__((address_space(1))) uint32_t*)g,
        (__attribute__((address_space(3))) uint32_t*)lds, 16, 0, 0);
}

// load 8 consecutive fp32 -> bf16x8 fragment (32B aligned source)
__device__ __forceinline__ bf16x8 frag8(const float* src) {
    float4 lo = ((const float4*)src)[0];
    float4 hi = ((const float4*)src)[1];
    bf16x8 r;
    r[0] = (bf16_t)lo.x; r[1] = (bf16_t)lo.y; r[2] = (bf16_t)lo.z; r[3] = (bf16_t)lo.w;
    r[4] = (bf16_t)hi.x; r[5] = (bf16_t)hi.y; r[6] = (bf16_t)hi.z; r[7] = (bf16_t)hi.w;
    return r;
}

// load 4+4 fp32 (two float4 at different bases) -> bf16x8 fragment
__device__ __forceinline__ bf16x8 frag44(const float* a, const float* b) {
    float4 lo = *(const float4*)a;
    float4 hi = *(const float4*)b;
    bf16x8 r;
    r[0] = (bf16_t)lo.x; r[1] = (bf16_t)lo.y; r[2] = (bf16_t)lo.z; r[3] = (bf16_t)lo.w;
    r[4] = (bf16_t)hi.x; r[5] = (bf16_t)hi.y; r[6] = (bf16_t)hi.z; r[7] = (bf16_t)hi.w;
    return r;
}

#define PIN asm volatile("" ::: "memory")

// ---------------------------------------------------------------------------
// Kernel 1: features = gelu(fe_w @ x + fe_b) -> bf16 pixel-major (permuted
// channel order cperm = g*16 + ot*4 + r  <->  ch = ot*16 + g*4 + r), + gf
// partials.  WAVE-PRIVATE double-buffered DMA pipeline, ZERO barriers:
//   each wave owns FOUR consecutive 64ch x 32px tiles; 2 x 8 KB private LDS
//   buffers; per-wave counted vmcnt (vmcnt is a per-wave counter, so the
//   pipeline needs no barriers and cannot be lockstep-coupled).
// A-fragments (fe_w) + bias loaded ONCE per 4 tiles (was: per tile).
// Ledger (per wave, in-order; S=8 DMA loads, V=4 stores, pins stop reorder):
//   A/bias .. S0 S1 | vmcnt(8)  -> A,bias,S0 retired (S1 in flight)
//   C0 V0, S2       | vmcnt(12) -> S1 retired (V0,S2 = 12 newest)
//   C1 V1, S3       | vmcnt(12) -> S2 retired (V1,S3 = 12 newest)
//   C2 V2           | vmcnt(4)  -> S3 retired (V2 = 4 newest)
//   C3 V3
// Chunk swizzle (GLOBAL-side): DMA instr s, lane l fetches chunk
// (l&7)^((s&3)<<1); reader column col -> dword ((col>>2)^(g<<1))*4+(col&3)
// within row -> 2-way bank aliasing only (free).
// Grid: 1024 blocks * 4 waves * 4 tiles = 16384 tiles of 32 px.
// LDS: 4 waves * 2 bufs * 8 KB = 64 KB -> 2 blocks/CU (8 waves/CU sustained).
// ---------------------------------------------------------------------------
__global__ __launch_bounds__(256, 2)
void k1_feat(const float* __restrict__ x, const float* __restrict__ fe_w,
             const float* __restrict__ fe_b, bf16_t* __restrict__ feat,
             float* __restrict__ gf_part) {
    __shared__ float xs[4][2][32 * 64];   // 64 KB
    __shared__ float gf4[4][64];

    int tid = threadIdx.x;
    int lane = tid & 63;
    int wid = tid >> 6;
    int r16 = lane & 15;
    int g = lane >> 4;
    int gtile0 = blockIdx.x * 16 + wid * 4;   // first of this wave's 4 tiles
    int b = gtile0 >> 9;                      // 512 tiles per sample
    int px0 = (gtile0 & 511) * 32;            // wave's pixel base (128 px run)

    // A fragments (fe_w as MFMA A: row = out-ch = r16, k = kh*32 + g*8 + j)
    bf16x8 A[4][2];
    f32x4 bias[4];
#pragma unroll
    for (int ot = 0; ot < 4; ++ot) {
#pragma unroll
        for (int kh = 0; kh < 2; ++kh)
            A[ot][kh] = frag8(fe_w + (ot * 16 + r16) * 64 + kh * 32 + g * 8);
        bias[ot] = *(const f32x4*)(fe_b + ot * 16 + g * 4);
    }
    PIN;  // pin A/bias loads BEFORE the DMAs so the vmcnt ledger holds

    float* xw = &xs[wid][0][0];
    int rl = lane >> 3;                       // row within 8-row group
    int ch0 = lane & 7;                       // 16B chunk (LDS-linear)

    auto STAGE = [&](int buf, int t) {
#pragma unroll
        for (int s = 0; s < 8; ++s) {
            int row = s * 8 + rl;
            int gch = ch0 ^ ((s & 3) << 1);   // pre-swizzled global chunk
            const float* gsrc = x + (size_t)(b * 64 + row) * HW + px0 + t * 32 + gch * 4;
            load16_to_lds(gsrc, xw + buf * 2048 + s * 256);  // uniform base/instr
        }
    };

    // swizzled column offsets for the two 16-px windows (a = 0, 1)
    int cm0 = ((((r16 >> 2) + 0) ^ (g << 1)) << 2) + (r16 & 3);
    int cm1 = ((((r16 >> 2) + 4) ^ (g << 1)) << 2) + (r16 & 3);

    float gfp[4][4] = {};
    bf16_t* featb = feat + (size_t)b * HW * 64;

    auto COMPUTE = [&](int buf, int t) {
        const float* xb = xw + buf * 2048;
        bf16x8 B00, B10, B01, B11;
#pragma unroll
        for (int j = 0; j < 8; ++j) {
            int ro0 = (g * 8 + j) * 32;
            int ro1 = (32 + g * 8 + j) * 32;
            B00[j] = (bf16_t)xb[ro0 + cm0];
            B10[j] = (bf16_t)xb[ro0 + cm1];
            B01[j] = (bf16_t)xb[ro1 + cm0];
            B11[j] = (bf16_t)xb[ro1 + cm1];
        }
        f32x4 y0[4], y1[4];
#pragma unroll
        for (int ot = 0; ot < 4; ++ot) {
            f32x4 z = {0.f, 0.f, 0.f, 0.f};
            z = __builtin_amdgcn_mfma_f32_16x16x32_bf16(A[ot][0], B00, z, 0, 0, 0);
            y0[ot] = __builtin_amdgcn_mfma_f32_16x16x32_bf16(A[ot][1], B01, z, 0, 0, 0);
            f32x4 w = {0.f, 0.f, 0.f, 0.f};
            w = __builtin_amdgcn_mfma_f32_16x16x32_bf16(A[ot][0], B10, w, 0, 0, 0);
            y1[ot] = __builtin_amdgcn_mfma_f32_16x16x32_bf16(A[ot][1], B11, w, 0, 0, 0);
        }
        // epilogue per 16-px window: gelu, gf accumulate, full-line stores
#pragma unroll
        for (int a = 0; a < 2; ++a) {
            f32x4* y = a ? y1 : y0;
            float vals[4][4];
#pragma unroll
            for (int ot = 0; ot < 4; ++ot)
#pragma unroll
                for (int r = 0; r < 4; ++r) {
                    float v = gelu_f(y[ot][r] + bias[ot][r]);
                    gfp[ot][r] += v;
                    vals[ot][r] = v;
                }
            uint4 lo, hi;
            lo.x = pk2(vals[0][0], vals[0][1]); lo.y = pk2(vals[0][2], vals[0][3]);
            lo.z = pk2(vals[1][0], vals[1][1]); lo.w = pk2(vals[1][2], vals[1][3]);
            hi.x = pk2(vals[2][0], vals[2][1]); hi.y = pk2(vals[2][2], vals[2][3]);
            hi.z = pk2(vals[3][0], vals[3][1]); hi.w = pk2(vals[3][2], vals[3][3]);
            int px = px0 + t * 32 + a * 16 + r16;
            uint4* dst = (uint4*)(featb + (size_t)px * 64 + g * 16);
            dst[0] = lo;                    // cperm g*16 + [0,8)
            dst[1] = hi;                    // cperm g*16 + [8,16)
        }
    };

    STAGE(0, 0);
    STAGE(1, 1);
    PIN;
    asm volatile("s_waitcnt vmcnt(8)" ::: "memory");
    COMPUTE(0, 0);
    PIN;
    STAGE(0, 2);
    PIN;
    asm volatile("s_waitcnt vmcnt(12)" ::: "memory");
    COMPUTE(1, 1);
    PIN;
    STAGE(1, 3);
    PIN;
    asm volatile("s_waitcnt vmcnt(12)" ::: "memory");
    COMPUTE(0, 2);
    PIN;
    asm volatile("s_waitcnt vmcnt(4)" ::: "memory");
    COMPUTE(1, 3);

    // cross-wave gf reduction -> per-block partial (one sync, end of block)
#pragma unroll
    for (int ot = 0; ot < 4; ++ot)
#pragma unroll
        for (int r = 0; r < 4; ++r) {
            float v = gfp[ot][r];
            v += __shfl_xor(v, 1);
            v += __shfl_xor(v, 2);
            v += __shfl_xor(v, 4);
            v += __shfl_xor(v, 8);
            if (r16 == 0) gf4[wid][ot * 16 + g * 4 + r] = v;
        }
    __syncthreads();
    if (tid < 64)
        gf_part[(size_t)blockIdx.x * 64 + tid] =
            gf4[0][tid] + gf4[1][tid] + gf4[2][tid] + gf4[3][tid];
}

// ---------------------------------------------------------------------------
// Kernel 2: gating MLP. One block per sample (grid=32). Reduces k1's 32
// per-block partials, then LDS-staged matvec chain (2-way split chains).
// ---------------------------------------------------------------------------
__global__ __launch_bounds__(256)
void k2_gate(const float* __restrict__ gf_part,
             const float* __restrict__ g1_w, const float* __restrict__ g1_b,
             const float* __restrict__ bn1_g, const float* __restrict__ bn1_b,
             const float* __restrict__ ca1_w, const float* __restrict__ ca1_b,
             const float* __restrict__ ca2_w, const float* __restrict__ ca2_b,
             const float* __restrict__ g2_w, const float* __restrict__ g2_b,
             const float* __restrict__ bn2_g, const float* __restrict__ bn2_b,
             const float* __restrict__ g3_w, const float* __restrict__ g3_b,
             int* __restrict__ gidx, float* __restrict__ gw) {
    __shared__ float w1t[128 * 65];    // g1_w padded
    __shared__ float wc1[8 * 129];     // ca1_w padded
    __shared__ float wc2[128 * 9];     // ca2_w padded
    __shared__ float w2t[64 * 129];    // g2_w padded
    __shared__ float w3[8 * 65];       // g3_w padded
    __shared__ float gf[64], h1[128], a1[8], hh[64], sc[8];
    const float R1 = 0.99999500003749969f;   // 1/sqrt(1+1e-5)
    int tid = threadIdx.x;
    int b = blockIdx.x;

    // stage weights: coalesced float4 global loads -> padded LDS rows
    for (int i = tid; i < 2048; i += 256) {        // g1_w [128][64]
        float4 v = ((const float4*)g1_w)[i];
        float* d = w1t + (i >> 4) * 65 + (i & 15) * 4;
        d[0] = v.x; d[1] = v.y; d[2] = v.z; d[3] = v.w;
    }
    for (int i = tid; i < 2048; i += 256) {        // g2_w [64][128]
        float4 v = ((const float4*)g2_w)[i];
        float* d = w2t + (i >> 5) * 129 + (i & 31) * 4;
        d[0] = v.x; d[1] = v.y; d[2] = v.z; d[3] = v.w;
    }
    if (tid < 256) {                               // ca1_w [8][128]
        int i = tid;
        float4 v = ((const float4*)ca1_w)[i];
        float* d = wc1 + (i >> 5) * 129 + (i & 31) * 4;
        d[0] = v.x; d[1] = v.y; d[2] = v.z; d[3] = v.w;
    }
    if (tid < 256) {                               // ca2_w [128][8]
        int i = tid;
        float4 v = ((const float4*)ca2_w)[i];
        float* d = wc2 + (i >> 1) * 9 + (i & 1) * 4;
        d[0] = v.x; d[1] = v.y; d[2] = v.z; d[3] = v.w;
    }
    if (tid < 128) {                               // g3_w [8][64]
        int i = tid;
        float4 v = ((const float4*)g3_w)[i];
        float* d = w3 + (i >> 4) * 65 + (i & 15) * 4;
        d[0] = v.x; d[1] = v.y; d[2] = v.z; d[3] = v.w;
    }
    if (tid < 64) {                                // reduce k1 partials (32)
        float s0 = 0.f, s1 = 0.f;
        const float* gp = gf_part + (size_t)b * 32 * 64 + tid;
#pragma unroll 8
        for (int i = 0; i < 32; i += 2) {
            s0 += gp[(size_t)(i + 0) * 64];
            s1 += gp[(size_t)(i + 1) * 64];
        }
        gf[tid] = (s0 + s1) * (1.0f / 16384.0f);
    }
    __syncthreads();

    if (tid < 128) {                 // h1 = gelu(bn(g1))
        int j = tid;
        float s0 = 0.f, s1 = 0.f;
#pragma unroll 8
        for (int c = 0; c < 64; c += 2) {
            s0 += gf[c] * w1t[j * 65 + c];
            s1 += gf[c + 1] * w1t[j * 65 + c + 1];
        }
        float s = g1_b[j] + s0 + s1;
        s = s * (bn1_g[j] * R1) + bn1_b[j];
        h1[j] = gelu_f(s);
    }
    __syncthreads();
    if (tid < 8) {                   // a1 = gelu(ca1)
        int j = tid;
        float s0 = 0.f, s1 = 0.f;
#pragma unroll 8
        for (int c = 0; c < 128; c += 2) {
            s0 += h1[c] * wc1[j * 129 + c];
            s1 += h1[c + 1] * wc1[j * 129 + c + 1];
        }
        a1[j] = gelu_f(ca1_b[j] + s0 + s1);
    }
    __syncthreads();
    if (tid < 128) {                 // h1 *= sigmoid(2*att)
        int j = tid;
        float s = ca2_b[j];
#pragma unroll
        for (int r = 0; r < 8; ++r) s += a1[r] * wc2[j * 9 + r];
        float e2 = __builtin_amdgcn_exp2f(-2.8853901f * s);  // 2*log2(e)
        h1[j] = h1[j] * __builtin_amdgcn_rcpf(1.0f + e2);
    }
    __syncthreads();
    if (tid < 64) {                  // hh = gelu(bn(g2))
        int j = tid;
        float s0 = 0.f, s1 = 0.f;
#pragma unroll 8
        for (int c = 0; c < 128; c += 2) {
            s0 += h1[c] * w2t[j * 129 + c];
            s1 += h1[c + 1] * w2t[j * 129 + c + 1];
        }
        float s = g2_b[j] + s0 + s1;
        s = s * (bn2_g[j] * R1) + bn2_b[j];
        hh[j] = gelu_f(s);
    }
    __syncthreads();
    if (tid < 8) {                   // scores
        int j = tid;
        float s0 = 0.f, s1 = 0.f;
#pragma unroll 8
        for (int c = 0; c < 64; c += 2) {
            s0 += hh[c] * w3[j * 65 + c];
            s1 += hh[c + 1] * w3[j * 65 + c + 1];
        }
        sc[j] = g3_b[j] + s0 + s1;
    }
    __syncthreads();
    if (tid == 0) {
        float v0 = -1e30f, v1 = -1e30f;
        int i0 = 0, i1 = 0;
#pragma unroll
        for (int e = 0; e < 8; ++e) {
            float s = sc[e];
            if (s > v0) { v1 = v0; i1 = i0; v0 = s; i0 = e; }
            else if (s > v1) { v1 = s; i1 = e; }
        }
        float t = __builtin_amdgcn_exp2f(0.7213475f * (v1 - v0));  // 0.5*log2(e)
        float den = __builtin_amdgcn_rcpf(1.0f + t);
        gidx[b * 2] = i0; gidx[b * 2 + 1] = i1;
        gw[b * 2] = den; gw[b * 2 + 1] = t * den;
    }
}

// ---------------------------------------------------------------------------
// Kernel 3: out = 0.5*(gelu(s0)+gelu(s1)) + w0*gelu(e[i0]) + w1*gelu(e[i1]).
// Operand-swapped MFMA: A = feat pixels (row=px=r16, k=cperm), B = weight
// fragment (col=out-ch=r16, k=cperm) -> D row = px = g*4+r, col = out-ch.
// feat's channel order is PERMUTED (cperm = G*16+ot*4+r <-> ch = ot*16+G*4+r);
// weight fragments apply the same k-permutation: j=0..3 at base, j=4..7 at
// base+16, base = (g&1)*32 + (kh*2+(g>>1))*4.
// Each lane owns 4 CONSECUTIVE pixels of one channel -> float4 stores.
// 2048 blocks (64 stripes of 256 px), depth-2 register prefetch.
// ---------------------------------------------------------------------------
__global__ __launch_bounds__(256, 4)
void k3_out(const bf16_t* __restrict__ feat, const float* __restrict__ s_w,
            const float* __restrict__ s_b, const float* __restrict__ e_w,
            const float* __restrict__ e_b, const int* __restrict__ gidx,
            const float* __restrict__ gw, float* __restrict__ out) {
    int tid = threadIdx.x;
    int lane = tid & 63, wid = tid >> 6;
    int r16 = lane & 15, g = lane >> 4;
    int b = blockIdx.x >> 6;
    int stripe = blockIdx.x & 63;

    int i0 = gidx[2 * b], i1 = gidx[2 * b + 1];
    float coef[4] = {0.5f, 0.5f, gw[2 * b], gw[2 * b + 1]};
    const float* Wm[4] = {s_w, s_w + 4096,
                          e_w + (size_t)i0 * 4096, e_w + (size_t)i1 * 4096};
    const float* Bv[4] = {s_b, s_b + 64, e_b + i0 * 64, e_b + i1 * 64};

    bf16x8 Wf[4][2];
    float bias[4];
    int row = wid * 16 + r16;                      // this lane's out-channel
#pragma unroll
    for (int m = 0; m < 4; ++m) {
#pragma unroll
        for (int kh = 0; kh < 2; ++kh) {
            int base = (g & 1) * 32 + (kh * 2 + (g >> 1)) * 4;
            Wf[m][kh] = frag44(Wm[m] + row * 64 + base,
                               Wm[m] + row * 64 + base + 16);
        }
        bias[m] = Bv[m][row];
    }

    const uint4* fb = (const uint4*)(feat + (size_t)b * HW * 64);
    float* outb = out + ((size_t)b * 64 + row) * HW + stripe * 256;
    int pbase = stripe * 256 + r16;

    auto BODY = [&](int t, uint4 u0, uint4 u1) {
        bf16x8 F0 = __builtin_bit_cast(bf16x8, u0);
        bf16x8 F1 = __builtin_bit_cast(bf16x8, u1);
        f32x4 acc = {0.f, 0.f, 0.f, 0.f};
#pragma unroll
        for (int m = 0; m < 4; ++m) {
            f32x4 y = {0.f, 0.f, 0.f, 0.f};
            y = __builtin_amdgcn_mfma_f32_16x16x32_bf16(F0, Wf[m][0], y, 0, 0, 0);
            y = __builtin_amdgcn_mfma_f32_16x16x32_bf16(F1, Wf[m][1], y, 0, 0, 0);
#pragma unroll
            for (int r = 0; r < 4; ++r)
                acc[r] += coef[m] * gelu_f(y[r] + bias[m]);
        }
        float4 st = {acc[0], acc[1], acc[2], acc[3]};
        *(float4*)(outb + t * 16 + g * 4) = st;     // 4 consecutive pixels
    };

    uint4 a0 = fb[(size_t)pbase * 8 + g];
    uint4 a1 = fb[(size_t)pbase * 8 + 4 + g];
    uint4 b0 = fb[(size_t)(pbase + 16) * 8 + g];
    uint4 b1 = fb[(size_t)(pbase + 16) * 8 + 4 + g];
#pragma unroll
    for (int t = 0; t < 14; t += 2) {
        uint4 n0 = fb[(size_t)(pbase + (t + 2) * 16) * 8 + g];
        uint4 n1 = fb[(size_t)(pbase + (t + 2) * 16) * 8 + 4 + g];
        BODY(t, a0, a1); a0 = n0; a1 = n1;
        uint4 m0 = fb[(size_t)(pbase + (t + 3) * 16) * 8 + g];
        uint4 m1 = fb[(size_t)(pbase + (t + 3) * 16) * 8 + 4 + g];
        BODY(t + 1, b0, b1); b0 = m0; b1 = m1;
    }
    BODY(14, a0, a1);
    BODY(15, b0, b1);
}

extern "C" void kernel_launch(void* const* d_in, const int* in_sizes, int n_in,
                              void* d_out, int out_size, void* d_ws, size_t ws_size,
                              hipStream_t stream) {
    (void)in_sizes; (void)n_in; (void)out_size; (void)ws_size;
    const float* x     = (const float*)d_in[0];
    const float* fe_w  = (const float*)d_in[1];
    const float* fe_b  = (const float*)d_in[2];
    const float* s_w   = (const float*)d_in[3];
    const float* s_b   = (const float*)d_in[4];
    const float* e_w   = (const float*)d_in[5];
    const float* e_b   = (const float*)d_in[6];
    const float* g1_w  = (const float*)d_in[7];
    const float* g1_b  = (const float*)d_in[8];
    const float* bn1_g = (const float*)d_in[9];
    const float* bn1_b = (const float*)d_in[10];
    const float* ca1_w = (const float*)d_in[11];
    const float* ca1_b = (const float*)d_in[12];
    const float* ca2_w = (const float*)d_in[13];
    const float* ca2_b = (const float*)d_in[14];
    const float* g2_w  = (const float*)d_in[15];
    const float* g2_b  = (const float*)d_in[16];
    const float* bn2_g = (const float*)d_in[17];
    const float* bn2_b = (const float*)d_in[18];
    const float* g3_w  = (const float*)d_in[19];
    const float* g3_b  = (const float*)d_in[20];
    float* out = (float*)d_out;

    char* wsb = (char*)d_ws;
    bf16_t* feat   = (bf16_t*)wsb;                            // 64 MiB bf16 features
    float* gf_part = (float*)(wsb + 67108864);                // 256 KiB partials
    int* gidx      = (int*)(wsb + 67108864 + 1048576);        // 256 B
    float* gwts    = (float*)(wsb + 67108864 + 1048576 + 256);// 256 B

    k1_feat<<<1024, 256, 0, stream>>>(x, fe_w, fe_b, feat, gf_part);
    k2_gate<<<32, 256, 0, stream>>>(gf_part, g1_w, g1_b, bn1_g, bn1_b, ca1_w, ca1_b,
                                    ca2_w, ca2_b, g2_w, g2_b, bn2_g, bn2_b, g3_w, g3_b,
                                    gidx, gwts);
    k3_out<<<2048, 256, 0, stream>>>(feat, s_w, s_b, e_w, e_b, gidx, gwts, out);
}